// Round 10
// baseline (168.202 us; speedup 1.0000x reference)
//
#include <hip/hip_runtime.h>
#include <hip/hip_bf16.h>

#define N_ROWS 32768
#define D_INP  256
#define NEXP   32
#define D_OUTP 256
#define TROWS  64
#define NBLK   512    // moe_gemm persistent blocks = 8 XCD * 64
#define GROWS  64     // gate rows per block

typedef __attribute__((ext_vector_type(4))) float f32x4;
typedef __attribute__((ext_vector_type(8))) short bf16x8;

__device__ inline unsigned short f2b(float f) {
    union { __hip_bfloat16 h; unsigned short u; } cv;
    cv.h = __float2bfloat16(f);
    return cv.u;
}
__device__ inline float b2f(unsigned short u) {
    union { unsigned v; float f; } c; c.v = ((unsigned)u) << 16; return c.f;
}

// ---------------------------------------------------------------------------
// Kernel 1: gate GEMM, register-blocked (unchanged from round 9).
// ---------------------------------------------------------------------------
__global__ __launch_bounds__(256) void gate_kernel(
    const float* __restrict__ x, const float* __restrict__ noise,
    const float* __restrict__ gw, const float* __restrict__ gb,
    const float* __restrict__ ew, unsigned short* __restrict__ wbT,
    unsigned short* __restrict__ xb, float* __restrict__ tkp,
    int* __restrict__ tki, float* __restrict__ esum, int* __restrict__ ecnt)
{
    __shared__ float rA[8448];        // gws[32][260]=8320f, then red[4][64][33]
    __shared__ float xs[64 * 68];
    __shared__ float lsum[NEXP];
    __shared__ int   lcnt[NEXP];

    int tid = threadIdx.x;
    int row0 = blockIdx.x * GROWS;

    #pragma unroll
    for (int it = 0; it < 8; ++it) {
        int q = it * 256 + tid;
        int e = q >> 6;
        int k = (q & 63) * 4;
        float4 v = ((const float4*)gw)[q];
        *(float4*)&rA[e * 260 + k] = v;
    }
    if (tid < NEXP) { lsum[tid] = 0.f; lcnt[tid] = 0; }

    int lane = tid & 63;
    int wid  = tid >> 6;
    int e4 = lane & 7;
    int rq = lane >> 3;

    float acc[8][4];
    #pragma unroll
    for (int m = 0; m < 8; m++)
        #pragma unroll
        for (int n = 0; n < 4; n++) acc[m][n] = 0.f;

    for (int s = 0; s < 4; ++s) {
        __syncthreads();
        #pragma unroll
        for (int it = 0; it < 4; ++it) {
            int q = it * 256 + tid;
            int r = q >> 4;
            int kq = q & 15;
            float4 v = *(const float4*)(x + (size_t)(row0 + r) * D_INP + s * 64 + kq * 4);
            *(float4*)&xs[r * 68 + kq * 4] = v;
            unsigned short b[4] = { f2b(v.x), f2b(v.y), f2b(v.z), f2b(v.w) };
            *(ushort4*)(xb + (size_t)(row0 + r) * D_INP + s * 64 + kq * 4) = *(ushort4*)b;
        }
        __syncthreads();
        int ko = s * 64 + wid * 16;
        #pragma unroll
        for (int c = 0; c < 4; ++c) {
            float4 wv[4];
            #pragma unroll
            for (int n = 0; n < 4; n++)
                wv[n] = *(float4*)&rA[(e4 + 8 * n) * 260 + ko + c * 4];
            #pragma unroll
            for (int m = 0; m < 8; m++) {
                float4 xv = *(float4*)&xs[(rq + 8 * m) * 68 + wid * 16 + c * 4];
                #pragma unroll
                for (int n = 0; n < 4; n++)
                    acc[m][n] = fmaf(xv.x, wv[n].x,
                                fmaf(xv.y, wv[n].y,
                                fmaf(xv.z, wv[n].z,
                                fmaf(xv.w, wv[n].w, acc[m][n]))));
            }
        }
    }
    __syncthreads();

    {
        int base = (wid * 64 + lane) * 33;
        #pragma unroll
        for (int m = 0; m < 8; m++)
            #pragma unroll
            for (int n = 0; n < 4; n++)
                rA[base + m * 4 + n] = acc[m][n];
    }
    __syncthreads();

    {
        int row = tid >> 2;
        int eo  = (tid & 3) * 8;
        int n   = tid & 3;
        int R = row0 + row;
        int j = (row >> 3) * 4 + n;
        int lpb = (row & 7) * 8;
        float4 nz0 = *(const float4*)(noise + (size_t)R * NEXP + eo);
        float4 nz1 = *(const float4*)(noise + (size_t)R * NEXP + eo + 4);
        float nz[8] = { nz0.x, nz0.y, nz0.z, nz0.w, nz1.x, nz1.y, nz1.z, nz1.w };
        float l[8], p[8];
        #pragma unroll
        for (int i = 0; i < 8; i++) {
            int a = (lpb + i) * 33 + j;
            float v = rA[a] + rA[2112 + a] + rA[4224 + a] + rA[6336 + a];
            l[i] = v + gb[eo + i] + 0.1f * nz[i];
        }
        float mx = l[0];
        #pragma unroll
        for (int i = 1; i < 8; i++) mx = fmaxf(mx, l[i]);
        mx = fmaxf(mx, __shfl_xor(mx, 1));
        mx = fmaxf(mx, __shfl_xor(mx, 2));
        float sum = 0.f;
        #pragma unroll
        for (int i = 0; i < 8; i++) { p[i] = expf(l[i] - mx); sum += p[i]; }
        sum += __shfl_xor(sum, 1);
        sum += __shfl_xor(sum, 2);
        float inv = 1.f / sum;
        #pragma unroll
        for (int i = 0; i < 8; i++) p[i] *= inv;

        float bp = p[0]; int bi = eo;
        #pragma unroll
        for (int i = 1; i < 8; i++) if (p[i] > bp) { bp = p[i]; bi = eo + i; }
        #pragma unroll
        for (int s2 = 1; s2 < 4; s2 <<= 1) {
            float op = __shfl_xor(bp, s2); int oi = __shfl_xor(bi, s2);
            if (op > bp || (op == bp && oi < bi)) { bp = op; bi = oi; }
        }
        float bp2 = -1.f; int bi2 = 0;
        #pragma unroll
        for (int i = 0; i < 8; i++) {
            int E = eo + i;
            float q = (E == bi) ? -1.f : p[i];
            if (q > bp2 || (q == bp2 && E < bi2)) { bp2 = q; bi2 = E; }
        }
        #pragma unroll
        for (int s2 = 1; s2 < 4; s2 <<= 1) {
            float op = __shfl_xor(bp2, s2); int oi = __shfl_xor(bi2, s2);
            if (op > bp2 || (op == bp2 && oi < bi2)) { bp2 = op; bi2 = oi; }
        }
        if ((tid & 3) == 0) {
            tkp[R * 2] = bp;  tkp[R * 2 + 1] = bp2;
            tki[R * 2] = bi;  tki[R * 2 + 1] = bi2;
            atomicAdd(&lcnt[bi], 1); atomicAdd(&lcnt[bi2], 1);
        }
        #pragma unroll
        for (int i = 0; i < 8; i++) atomicAdd(&lsum[eo + i], p[i]);
    }

    #pragma unroll
    for (int it = 0; it < 2; ++it) {
        int fid = blockIdx.x * 512 + it * 256 + tid;
        int row = fid >> 5;
        int kc  = fid & 31;
        const float4* sp = (const float4*)(ew + (size_t)row * D_INP + kc * 8);
        float4 v0 = sp[0], v1 = sp[1];
        unsigned short t[8] = { f2b(v0.x), f2b(v0.y), f2b(v0.z), f2b(v0.w),
                                f2b(v1.x), f2b(v1.y), f2b(v1.z), f2b(v1.w) };
        int e  = row >> 8;
        int rr = row & 255;
        int q  = rr >> 6;
        int nn = (rr >> 4) & 3;
        int lr = rr & 15;
        int kk = kc >> 2;
        int kg = kc & 3;
        size_t off = ((((size_t)(e * 4 + q) * 8 + kk) * 4 + nn) * 64 + kg * 16 + lr) * 8;
        *(uint4*)(wbT + off) = *(uint4*)t;
    }

    __syncthreads();
    if (tid < NEXP) {
        unsafeAtomicAdd(&esum[tid], lsum[tid]);
        atomicAdd(&ecnt[tid], lcnt[tid]);
    }
}

// ---------------------------------------------------------------------------
// Kernel 2: build_list (unchanged from round 9).
// ---------------------------------------------------------------------------
__global__ __launch_bounds__(1024) void build_list_kernel(
    const int* __restrict__ tki, const float* __restrict__ esum,
    const int* __restrict__ ecnt, int* __restrict__ cursor0,
    int* __restrict__ list, float* __restrict__ loss_out)
{
    __shared__ int lcnt[NEXP], lbase[NEXP], s_offs[NEXP + 1];
    int tid = threadIdx.x;
    if (tid < NEXP) lcnt[tid] = 0;
    if (tid < 32) {
        int c = ecnt[tid];
        int ic = c;
        #pragma unroll
        for (int s = 1; s < 32; s <<= 1) {
            int a = __shfl_up(ic, s, 32);
            if (tid >= s) ic += a;
        }
        s_offs[tid + 1] = ic;
        if (tid == 0) s_offs[0] = 0;
    }
    __syncthreads();
    int r = blockIdx.x * 1024 + tid;
    int e0 = tki[r * 2], e1 = tki[r * 2 + 1];
    int p0 = atomicAdd(&lcnt[e0], 1);
    int p1 = atomicAdd(&lcnt[e1], 1);
    __syncthreads();
    if (tid < NEXP) lbase[tid] = s_offs[tid] + atomicAdd(&cursor0[tid], lcnt[tid]);
    __syncthreads();
    list[lbase[e0] + p0] = r * 2;
    list[lbase[e1] + p1] = r * 2 + 1;

    if (blockIdx.x == 0 && tid < 32) {
        float d = esum[tid] * (1.f / N_ROWS) - (1.f / NEXP);
        float v = d * d;
        #pragma unroll
        for (int s = 16; s > 0; s >>= 1) v += __shfl_xor(v, s, 32);
        if (tid == 0) *loss_out = v;
    }
}

// ---------------------------------------------------------------------------
// Kernel 3: grouped expert GEMM v5 — persistent per-(expert, j0) blocks.
// 512 blocks: e = bs>>4, j0 = bs&15; block owns tiles {j0, j0+16, ...} of
// expert e (64 rows x 256 cols each). Per super-round of 2 tiles: stage row
// tables once; pipeline A-gather of tile t+1 (global->regs) under tile t's
// MFMA phase (T14). XCD swizzle keeps each XCD on 4 experts -> W L2-resident.
// ---------------------------------------------------------------------------
__global__ __launch_bounds__(256) void moe_gemm_kernel(
    const unsigned short* __restrict__ xb, const unsigned short* __restrict__ wbT,
    const float* __restrict__ expb, const float* __restrict__ tkp,
    const int* __restrict__ list, const int* __restrict__ ecnt,
    unsigned short* __restrict__ y0, unsigned short* __restrict__ y1)
{
    __shared__ int s_offs[NEXP + 1];
    __shared__ unsigned short xa[TROWS * 256];   // 32 KB, dual-use
    __shared__ int   entT[2][TROWS];
    __shared__ float sprobT[2][TROWS];

    int tid = threadIdx.x;
    if (tid < 32) {
        int c = ecnt[tid];
        int ic = c;
        #pragma unroll
        for (int s = 1; s < 32; s <<= 1) {
            int a = __shfl_up(ic, s, 32);
            if (tid >= s) ic += a;
        }
        s_offs[tid + 1] = ic;
        if (tid == 0) s_offs[0] = 0;
    }
    __syncthreads();

    // bijective XCD swizzle: NBLK = 8 * 64
    int bs = (blockIdx.x & 7) * 64 + (blockIdx.x >> 3);
    int e  = bs >> 4;
    int j0 = bs & 15;
    int base  = s_offs[e];
    int cnt   = s_offs[e + 1] - base;
    int ntile = (cnt + TROWS - 1) >> 6;
    if (j0 >= ntile) return;    // uniform exit (e, j0, ntile block-uniform)

    int wave = tid >> 6;
    int lane = tid & 63;
    int lr = lane & 15;
    int kg = lane >> 4;
    int n0 = wave * 64;
    int sr = tid >> 2;          // staging row (4 threads/row)
    int sc = tid & 3;
    int swz = sr & 7;
    int aswz = lr & 7;

    const unsigned short* wbase = wbT + (size_t)(e * 4 + wave) * 32 * 512;
    float bias[4];
    #pragma unroll
    for (int nn = 0; nn < 4; nn++) bias[nn] = expb[e * 256 + n0 + nn * 16 + lr];

    uint4 areg[8];

    for (int t0 = j0; t0 < ntile; t0 += 32) {
        // stage row tables for tiles {t0, t0+16}
        if (tid < 128) {
            int p = tid >> 6, r = tid & 63;
            int tp = t0 + p * 16;
            int ent = -1; float pr = 0.f;
            if (tp < ntile && r < cnt - tp * TROWS) {
                ent = list[base + tp * TROWS + r];
                pr  = tkp[ent];
            }
            entT[p][r] = ent; sprobT[p][r] = pr;
        }
        __syncthreads();

        // prefetch A for first tile of this super-round
        {
            int ent = entT[0][sr];
            int gr = ent < 0 ? 0 : (ent >> 1);
            const uint4* src = (const uint4*)(xb + (size_t)gr * D_INP);
            #pragma unroll
            for (int i = 0; i < 8; ++i) areg[i] = src[sc + 4 * i];
        }

        for (int p = 0; p < 2; ++p) {
            int tp = t0 + p * 16;
            if (tp >= ntile) break;   // uniform

            // write prefetched A -> xa (chunk-XOR swizzle)
            {
                uint4* dst = (uint4*)xa;
                #pragma unroll
                for (int i = 0; i < 8; ++i) {
                    int c = sc + 4 * i;
                    dst[sr * 32 + (c ^ swz)] = areg[i];
                }
            }
            __syncthreads();   // B1: xa visible

            // issue next tile's A-gather (hides under MFMA)
            if (p == 0 && t0 + 16 < ntile) {
                int ent = entT[1][sr];
                int gr = ent < 0 ? 0 : (ent >> 1);
                const uint4* src = (const uint4*)(xb + (size_t)gr * D_INP);
                #pragma unroll
                for (int i = 0; i < 8; ++i) areg[i] = src[sc + 4 * i];
            }

            f32x4 acc[4][4];
            #pragma unroll
            for (int mm = 0; mm < 4; mm++)
                #pragma unroll
                for (int nn = 0; nn < 4; nn++)
                    acc[mm][nn] = (f32x4){0.f, 0.f, 0.f, 0.f};

            #pragma unroll
            for (int kk = 0; kk < 8; kk++) {
                int chunk = kk * 4 + kg;
                bf16x8 a[4], bb[4];
                #pragma unroll
                for (int mm = 0; mm < 4; mm++)
                    a[mm] = *(const bf16x8*)&xa[(mm * 16 + lr) * 256 + ((chunk ^ aswz) * 8)];
                #pragma unroll
                for (int nn = 0; nn < 4; nn++)
                    bb[nn] = *(const bf16x8*)(wbase + (kk * 4 + nn) * 512 + lane * 8);
                #pragma unroll
                for (int mm = 0; mm < 4; mm++)
                    #pragma unroll
                    for (int nn = 0; nn < 4; nn++)
                        acc[mm][nn] = __builtin_amdgcn_mfma_f32_16x16x32_bf16(a[mm], bb[nn], acc[mm][nn], 0, 0, 0);
            }
            __syncthreads();   // B2: all xa reads done

            // epilogue: (acc + bias) * prob -> bf16 into xa
            #pragma unroll
            for (int mm = 0; mm < 4; mm++) {
                #pragma unroll
                for (int j = 0; j < 4; j++) {
                    int lrow = mm * 16 + kg * 4 + j;
                    float pp = sprobT[p][lrow];
                    #pragma unroll
                    for (int nn = 0; nn < 4; nn++) {
                        float v = (acc[mm][nn][j] + bias[nn]) * pp;
                        xa[lrow * 256 + n0 + nn * 16 + lr] = f2b(v);
                    }
                }
            }
            __syncthreads();   // B3: out-staged xa visible

            // store: 4 threads/row, contiguous 16B chunks
            {
                int ent = entT[p][sr];
                if (ent >= 0) {
                    unsigned short* dstb = ((ent & 1) ? y1 : y0) + (size_t)(ent >> 1) * D_OUTP;
                    const uint4* src = (const uint4*)(xa + sr * 256);
                    uint4* dst = (uint4*)dstb;
                    #pragma unroll
                    for (int i = 0; i < 8; ++i) {
                        int c = sc + 4 * i;
                        dst[c] = src[c];
                    }
                }
            }
            __syncthreads();   // B4: store's LDS reads done before next xa write
        }
    }
}

// ---------------------------------------------------------------------------
// Kernel 4: out = f32(y0) + f32(y1), streaming (unchanged).
// ---------------------------------------------------------------------------
__global__ __launch_bounds__(256) void combine_kernel(
    const unsigned short* __restrict__ y0, const unsigned short* __restrict__ y1,
    float* __restrict__ out)
{
    size_t i = ((size_t)blockIdx.x * 256 + threadIdx.x) * 8;
    uint4 a = *(const uint4*)(y0 + i);
    uint4 b = *(const uint4*)(y1 + i);
    const unsigned short* ap = (const unsigned short*)&a;
    const unsigned short* bp = (const unsigned short*)&b;
    float4 o0, o1;
    o0.x = b2f(ap[0]) + b2f(bp[0]);
    o0.y = b2f(ap[1]) + b2f(bp[1]);
    o0.z = b2f(ap[2]) + b2f(bp[2]);
    o0.w = b2f(ap[3]) + b2f(bp[3]);
    o1.x = b2f(ap[4]) + b2f(bp[4]);
    o1.y = b2f(ap[5]) + b2f(bp[5]);
    o1.z = b2f(ap[6]) + b2f(bp[6]);
    o1.w = b2f(ap[7]) + b2f(bp[7]);
    *(float4*)(out + i)     = o0;
    *(float4*)(out + i + 4) = o1;
}

// ---------------------------------------------------------------------------
extern "C" void kernel_launch(void* const* d_in, const int* in_sizes, int n_in,
                              void* d_out, int out_size, void* d_ws, size_t ws_size,
                              hipStream_t stream)
{
    const float* x   = (const float*)d_in[0];
    const float* noi = (const float*)d_in[1];
    const float* gw  = (const float*)d_in[2];
    const float* gb  = (const float*)d_in[3];
    const float* ew  = (const float*)d_in[4];
    const float* eb  = (const float*)d_in[5];
    float* out = (float*)d_out;

    char* p = (char*)d_ws;
    unsigned short* xb  = (unsigned short*)p; p += (size_t)N_ROWS * D_INP * 2;
    unsigned short* wbT = (unsigned short*)p; p += (size_t)NEXP * D_OUTP * D_INP * 2;
    unsigned short* y0  = (unsigned short*)p; p += (size_t)N_ROWS * D_OUTP * 2;
    unsigned short* y1  = (unsigned short*)p; p += (size_t)N_ROWS * D_OUTP * 2;
    float* tkp  = (float*)p; p += (size_t)N_ROWS * 2 * 4;
    int*   tki  = (int*)p;   p += (size_t)N_ROWS * 2 * 4;
    int*   list = (int*)p;   p += (size_t)N_ROWS * 2 * 4;
    float* esum = (float*)p; p += 32 * 4;
    int*   ecnt = (int*)p;   p += 32 * 4;
    int*   cur0 = (int*)p;   p += 32 * 4;

    hipMemsetAsync(esum, 0, 3 * 32 * 4, stream);   // esum + ecnt + cursor0

    gate_kernel<<<N_ROWS / GROWS, 256, 0, stream>>>(x, noi, gw, gb, ew, wbT, xb, tkp, tki, esum, ecnt);
    build_list_kernel<<<N_ROWS / 1024, 1024, 0, stream>>>(tki, esum, ecnt, cur0, list, out + (size_t)N_ROWS * D_OUTP);
    moe_gemm_kernel<<<NBLK, 256, 0, stream>>>(xb, wbT, eb, tkp, list, ecnt, y0, y1);
    combine_kernel<<<N_ROWS * D_OUTP / 8 / 256, 256, 0, stream>>>(y0, y1, out);
}